// Round 8
// baseline (386.893 us; speedup 1.0000x reference)
//
#include <hip/hip_runtime.h>
#include <math.h>

#define NEG_SLOPE 0.2f

typedef __attribute__((ext_vector_type(8))) short short8;
typedef __attribute__((ext_vector_type(4))) float f32x4;
typedef unsigned short ushort_t;
typedef unsigned int u32;
typedef __attribute__((ext_vector_type(8))) unsigned short ushort8;
typedef __attribute__((ext_vector_type(4))) unsigned short ushort4v;

__device__ inline ushort_t f2bf(float f) {
    unsigned int u = __builtin_bit_cast(unsigned int, f);
    u += 0x7fffu + ((u >> 16) & 1u);   // RNE
    return (ushort_t)(u >> 16);
}
__device__ inline float bf2f(ushort_t u) {
    unsigned int v = ((unsigned int)u) << 16;
    return __builtin_bit_cast(float, v);
}

// async global->LDS, 16B per lane; LDS dest is wave-uniform base + lane*16 (m97 pattern)
__device__ inline void gl_lds16(const ushort_t* g, ushort_t* l) {
    __builtin_amdgcn_global_load_lds((const __attribute__((address_space(1))) u32*)g,
                                     (__attribute__((address_space(3))) u32*)l, 16, 0, 0);
}

// bijective XCD swizzle (m204): default dispatch round-robins XCDs (id%8); remap so each
// XCD owns a CONTIGUOUS chunk of tile-ids -> blocks sharing an A-panel sit on one L2.
__device__ inline int xcd_swizzle(int id, int nwg) {
    int q = nwg >> 3, r = nwg & 7;
    int xcd = id & 7, j = id >> 3;
    return (xcd < r ? xcd * (q + 1) : r * (q + 1) + (xcd - r) * q) + j;
}

// r20: BK=64 LDS tiles (row stride 128B) with XOR bank-swizzle (G4 / rule #21):
// linear gl_lds dest + inverse-permuted per-lane GLOBAL source + swizzled ds_read.
// LDS ushort index for (row, col-byte) under swizzle byte^=((row&7)<<4):
__device__ inline int swz_us(int row, int colb) {
    return row * 64 + ((colb ^ ((row & 7) << 4)) >> 1);
}

// ---------------- CSR build (discrete — r13: grid.sync ~60us each on MI355X) ------------
// r18: also computes W1as/W1ad[64x4] = per-head W1 @ a_{src,dst} (f32), enabling the
// layer-1 aggregate-then-transform trick (scores from x directly, no h1 materialization).

__global__ void convert_count_kernel(const int* __restrict__ ei, int E, int N,
                                     int* __restrict__ deg,
                                     const float* __restrict__ x, ushort_t* __restrict__ xb, int n4x,
                                     const float* __restrict__ W1, ushort_t* __restrict__ W1t,
                                     const float* __restrict__ W2, ushort_t* __restrict__ W2t,
                                     const float* __restrict__ W3, ushort_t* __restrict__ W3t,
                                     const float* __restrict__ cW1, ushort_t* __restrict__ cW1t,
                                     const float* __restrict__ as1, const float* __restrict__ ad1,
                                     float* __restrict__ W1as, float* __restrict__ W1ad) {
    int i = blockIdx.x * blockDim.x + threadIdx.x;
    if (i < E + N) {
        int d = (i < E) ? ei[E + i] : (i - E);
        atomicAdd(&deg[d], 1);
    }
    if (i < n4x) {
        float4 v = ((const float4*)x)[i];
        ushort4v o;
        o.x = f2bf(v.x); o.y = f2bf(v.y); o.z = f2bf(v.z); o.w = f2bf(v.w);
        ((ushort4v*)xb)[i] = o;
        return;
    }
    int j = i - n4x;
    if (j < 64 * 512) {
        int k = j / 512, nn = j % 512;
        W1t[(size_t)nn * 64 + k] = f2bf(W1[j]);
        return;
    }
    j -= 64 * 512;
    if (j < 512 * 512) {
        int k = j / 512, nn = j % 512;
        W2t[(size_t)nn * 512 + k] = f2bf(W2[j]);
        return;
    }
    j -= 512 * 512;
    if (j < 512 * 128) {
        int k = j / 128, nn = j % 128;
        W3t[(size_t)nn * 512 + k] = f2bf(W3[j]);
        return;
    }
    j -= 512 * 128;
    if (j < 128 * 64) {
        int k = j / 64, nn = j % 64;
        cW1t[(size_t)nn * 128 + k] = f2bf(cW1[j]);
        return;
    }
    j -= 128 * 64;
    if (j < 512) {
        // W1as[k,h] = sum_c W1[k, h*128+c] * as1[h,c]   (f32, exact fold)
        int k = j >> 3;          // 0..63
        int idx = j & 7;         // 0..7: h = idx&3, sel = idx>>2
        int h = idx & 3;
        int sel = idx >> 2;
        const float* av = sel ? ad1 : as1;
        float* outw = sel ? W1ad : W1as;
        const float* wrow = W1 + (size_t)k * 512 + h * 128;
        const float* arow = av + h * 128;
        float acc = 0.f;
        for (int c = 0; c < 128; c++) acc += wrow[c] * arow[c];
        outw[k * 4 + h] = acc;
    }
}

__global__ void scan1_kernel(const int* __restrict__ deg, int* __restrict__ rowptr,
                             int* __restrict__ bsum, int N) {
    __shared__ int sdata[256];
    int t = threadIdx.x;
    int base = blockIdx.x * 1024 + t * 4;
    int v[4];
#pragma unroll
    for (int k = 0; k < 4; k++) v[k] = (base + k < N) ? deg[base + k] : 0;
    int s = v[0] + v[1] + v[2] + v[3];
    sdata[t] = s;
    __syncthreads();
    for (int off = 1; off < 256; off <<= 1) {
        int x = (t >= off) ? sdata[t - off] : 0;
        __syncthreads();
        sdata[t] += x;
        __syncthreads();
    }
    int p = sdata[t] - s;
    if (t == 255) bsum[blockIdx.x] = sdata[255];
#pragma unroll
    for (int k = 0; k < 4; k++) {
        if (base + k < N) rowptr[base + k] = p;
        p += v[k];
    }
}

__global__ void scan2_kernel(int* __restrict__ bsum, int* __restrict__ rowptr, int nb, int N) {
    __shared__ int sh[256];
    int t = threadIdx.x;
    int v = (t < nb) ? bsum[t] : 0;
    sh[t] = v;
    __syncthreads();
    for (int off = 1; off < 256; off <<= 1) {
        int x = (t >= off) ? sh[t - off] : 0;
        __syncthreads();
        sh[t] += x;
        __syncthreads();
    }
    if (t < nb) bsum[t] = sh[t] - v;
    if (t == 255) rowptr[N] = sh[255];
}

__global__ void scan3_kernel(const int* __restrict__ bsum, int* __restrict__ rowptr,
                             int* __restrict__ cursor, int N) {
    int i = blockIdx.x * blockDim.x + threadIdx.x;
    if (i < N) {
        int v = rowptr[i] + bsum[i >> 10];
        rowptr[i] = v;
        cursor[i] = v;
    }
}

__global__ void fill_csr_kernel(const int* __restrict__ ei, int E, int N,
                                int* __restrict__ cursor, int* __restrict__ srcS) {
    int e = blockIdx.x * blockDim.x + threadIdx.x;
    if (e >= E + N) return;
    int s, d;
    if (e < E) { s = ei[e]; d = ei[E + e]; }
    else       { s = e - E; d = e - E; }
    int pos = atomicAdd(&cursor[d], 1);
    srcS[pos] = s;
}

// ---------------- layer-1 scores directly from x: s = x @ W1as, d = x @ W1ad ------------

__global__ __launch_bounds__(256) void score1_kernel(const ushort_t* __restrict__ xb,
                                                     const float* __restrict__ W1as,
                                                     const float* __restrict__ W1ad,
                                                     float* __restrict__ sOut,
                                                     float* __restrict__ dOut, int N) {
    __shared__ float wa[256];
    __shared__ float wd[256];
    int t = threadIdx.x;
    wa[t] = W1as[t];
    wd[t] = W1ad[t];
    __syncthreads();
    int n = blockIdx.x * 256 + t;
    if (n >= N) return;
    const ushort_t* xr = xb + (size_t)n * 64;
    float s_[4] = {0.f, 0.f, 0.f, 0.f};
    float d_[4] = {0.f, 0.f, 0.f, 0.f};
#pragma unroll
    for (int k8 = 0; k8 < 8; k8++) {
        ushort8 xv = *(const ushort8*)(xr + k8 * 8);
#pragma unroll
        for (int kk = 0; kk < 8; kk++) {
            float xf = bf2f(xv[kk]);
            int k = k8 * 8 + kk;
#pragma unroll
            for (int h = 0; h < 4; h++) {
                s_[h] += xf * wa[k * 4 + h];
                d_[h] += xf * wd[k * 4 + h];
            }
        }
    }
#pragma unroll
    for (int h = 0; h < 4; h++) {
        sOut[(size_t)n * 4 + h] = s_[h];
        dOut[(size_t)n * 4 + h] = d_[h];
    }
}

// ---------------- layer-1 aggregate-then-transform: aggX[n,h,64] = norm(sum alpha x[src])
// 32 threads/node: h = c>>3 owns dims (c&7)*8..+8 of head h; alpha-phase thread c covers
// (edge c&7, head c>>3). Gather is 128B/edge (x row) vs 1KB (h1 row) — 8x less traffic,
// and the 6.4MB x array is L2-resident.

__global__ void agg1x_kernel(const ushort_t* __restrict__ xb, const float* __restrict__ s,
                             const float* __restrict__ dv, const int* __restrict__ rowptr,
                             const int* __restrict__ srcS, ushort_t* __restrict__ outp, int N) {
    int c = threadIdx.x & 31;
    int slot = threadIdx.x >> 5;
    int n = blockIdx.x * 8 + slot;
    if (n >= N) return;
    int h = c >> 3;
    int d8 = c & 7;
    float dn = dv[(size_t)n * 4 + h];
    int beg = rowptr[n], end = rowptr[n + 1];
    float acc[8] = {0.f, 0.f, 0.f, 0.f, 0.f, 0.f, 0.f, 0.f};
    float den = 0.f;
    for (int cb = beg; cb < end; cb += 8) {
        int j = cb + d8;   // d8 doubles as my alpha-edge index
        int svg = 0;
        float al = 0.f;
        if (j < end) {
            svg = srcS[j];
            float e = s[(size_t)svg * 4 + h] + dn;
            e = (e >= 0.f) ? e : NEG_SLOPE * e;
            al = expf(fminf(e, 80.f));
        }
        int kmax = end - cb;
        if (kmax > 8) kmax = 8;
        for (int q = 0; q < kmax; q++) {
            float a = __shfl(al, h * 8 + q, 32);   // alpha(edge q, my head)
            int sq = __shfl(svg, q, 32);           // src(edge q) from lane q (head 0)
            den += a;
            ushort8 xv = *(const ushort8*)(xb + (size_t)sq * 64 + d8 * 8);
#pragma unroll
            for (int kk = 0; kk < 8; kk++) acc[kk] += a * bf2f(xv[kk]);
        }
    }
    float inv = 1.f / den;
    ushort8 o;
#pragma unroll
    for (int kk = 0; kk < 8; kk++) o[kk] = f2bf(acc[kk] * inv);
    ((ushort8*)outp)[(size_t)n * 32 + c] = o;   // out row [N,256]: h*64 + d8*8
}

// ---------------- layer-1 transform: Bb[n,512] = relu(blockdiag(aggX) @ W1 + b1) --------
// Output col-block = head; A cols = [head*64, head*64+64), lda=256. K=64 -> single BK=64
// step (r20), 2 barriers total. XOR-swizzled LDS (see r20 note at top).

__global__ __launch_bounds__(256, 2) void tgemm1_kernel(
    const ushort_t* __restrict__ A, const ushort_t* __restrict__ Bt,
    const float* __restrict__ bias, ushort_t* __restrict__ C, int M) {
    __shared__ ushort_t As[128 * 64];
    __shared__ ushort_t Bs[128 * 64];
    int wg = xcd_swizzle(blockIdx.x, gridDim.x);
    int bm = (wg >> 2) * 128;
    int head = wg & 3;
    int bn = head * 128;
    int tid = threadIdx.x;
    int w = tid >> 6, lane = tid & 63;
    int wy = w >> 1, wx = w & 1;
    int r = lane & 15, quad = lane >> 4;
    int srow = lane >> 3;                       // 0..7
    int scol = ((lane & 7) ^ srow) << 3;        // inverse-permuted source col (ushorts)
    f32x4 acc[4][4] = {};
#pragma unroll
    for (int it = 0; it < 4; it++) {
        int rowb = it * 32 + w * 8;
        gl_lds16(A  + (size_t)(bm + rowb + srow) * 256 + head * 64 + scol, As + rowb * 64);
        gl_lds16(Bt + (size_t)(bn + rowb + srow) * 64 + scol, Bs + rowb * 64);
    }
    __syncthreads();
#pragma unroll
    for (int kh = 0; kh < 2; kh++) {
        short8 af[4], bfr[4];
        int colb = kh * 64 + quad * 16;
#pragma unroll
        for (int i = 0; i < 4; i++)
            af[i] = *(const short8*)(As + swz_us(wy * 64 + i * 16 + r, colb));
#pragma unroll
        for (int j = 0; j < 4; j++)
            bfr[j] = *(const short8*)(Bs + swz_us(wx * 64 + j * 16 + r, colb));
#pragma unroll
        for (int i = 0; i < 4; i++)
#pragma unroll
            for (int j = 0; j < 4; j++)
                acc[i][j] = __builtin_amdgcn_mfma_f32_16x16x32_bf16(af[i], bfr[j], acc[i][j], 0, 0, 0);
    }
#pragma unroll
    for (int i = 0; i < 4; i++) {
        int rowb = bm + wy * 64 + i * 16 + quad * 4;
#pragma unroll
        for (int j = 0; j < 4; j++) {
            int col = bn + wx * 64 + j * 16 + r;
            float bv = bias[col];
#pragma unroll
            for (int reg = 0; reg < 4; reg++) {
                int row = rowb + reg;
                if (row < M) C[(size_t)row * 512 + col] = f2bf(fmaxf(acc[i][j][reg] + bv, 0.f));
            }
        }
    }
}

// ---------------- bf16 MFMA GEMM w/ global_load_lds staging + optional fused scores -----
// r19: 1D grid + bijective XCD swizzle (T1).
// r20: BK=64 + XOR-swizzled LDS (quarter-wave 8-way conflict -> 2-way free).
// r21: 2-phase double-buffered staging (T3 minimum recipe): issue next-tile
// global_load_lds BEFORE current tile's ds_read+MFMA; ONE barrier per tile (was 2).
// Buffer reuse guarded by the intervening barrier (each wave's lgkmcnt(0) before the
// barrier completes its reads of buf[cur] before buf[cur] is restaged 2 tiles later).
// LDS 64KB/block -> still 2 blocks/CU. MFMA order ascending k: bit-identical.

template <bool SCORES>
__global__ __launch_bounds__(256, 2) void gemm_bf16_kernel(
    const ushort_t* __restrict__ A, const ushort_t* __restrict__ Bt,
    ushort_t* __restrict__ C,
    const float* __restrict__ a_s, const float* __restrict__ a_d,
    float* __restrict__ sOut, float* __restrict__ dOut, int H,
    int M, int Ncols, int K, int nbx) {
    __shared__ ushort_t As[2][128 * 64];
    __shared__ ushort_t Bs[2][128 * 64];
    __shared__ float sL[2][128];
    __shared__ float dL[2][128];
    int wg = xcd_swizzle(blockIdx.x, gridDim.x);
    int bm = (wg / nbx) * 128, bn = (wg % nbx) * 128;
    int tid = threadIdx.x;
    int w = tid >> 6, lane = tid & 63;
    int wy = w >> 1, wx = w & 1;
    int r = lane & 15, quad = lane >> 4;
    int srow = lane >> 3;                       // 0..7
    int scol = ((lane & 7) ^ srow) << 3;        // inverse-permuted source col (ushorts)
    f32x4 acc[4][4] = {};

    const ushort_t* Arow = A  + (size_t)bm * K;
    const ushort_t* Brow = Bt + (size_t)bn * K;

    auto STAGE = [&](int buf, int k0) {
#pragma unroll
        for (int it = 0; it < 4; it++) {
            int rowb = it * 32 + w * 8;
            gl_lds16(Arow + (size_t)(rowb + srow) * K + k0 + scol, As[buf] + rowb * 64);
            gl_lds16(Brow + (size_t)(rowb + srow) * K + k0 + scol, Bs[buf] + rowb * 64);
        }
    };
    auto COMPUTE = [&](int buf) {
#pragma unroll
        for (int kh = 0; kh < 2; kh++) {
            short8 af[4], bfr[4];
            int colb = kh * 64 + quad * 16;
#pragma unroll
            for (int i = 0; i < 4; i++)
                af[i] = *(const short8*)(As[buf] + swz_us(wy * 64 + i * 16 + r, colb));
#pragma unroll
            for (int j = 0; j < 4; j++)
                bfr[j] = *(const short8*)(Bs[buf] + swz_us(wx * 64 + j * 16 + r, colb));
#pragma unroll
            for (int i = 0; i < 4; i++)
#pragma unroll
                for (int j = 0; j < 4; j++)
                    acc[i][j] = __builtin_amdgcn_mfma_f32_16x16x32_bf16(af[i], bfr[j], acc[i][j], 0, 0, 0);
        }
    };

    // prologue: stage tile 0; barrier drains it (vmcnt(0) implicit in __syncthreads)
    STAGE(0, 0);
    __syncthreads();
    int cur = 0;
    for (int k0 = 0; k0 < K; k0 += 64) {
        if (k0 + 64 < K) STAGE(cur ^ 1, k0 + 64);   // issue next tile FIRST (overlaps MFMA)
        COMPUTE(cur);
        __syncthreads();                            // drains next-tile loads; protects reuse
        cur ^= 1;
    }

#pragma unroll
    for (int i = 0; i < 4; i++) {
        int rowb = bm + wy * 64 + i * 16 + quad * 4;
#pragma unroll
        for (int j = 0; j < 4; j++) {
            int col = bn + wx * 64 + j * 16 + r;
            if (col >= Ncols) continue;
#pragma unroll
            for (int reg = 0; reg < 4; reg++) {
                int row = rowb + reg;
                if (row < M) C[(size_t)row * Ncols + col] = f2bf(acc[i][j][reg]);
            }
        }
    }
    if (SCORES) {
        int head = bn >> 7;
        float av[4], bv[4];
#pragma unroll
        for (int j = 0; j < 4; j++) {
            int c = wx * 64 + j * 16 + r;
            av[j] = a_s[head * 128 + c];
            bv[j] = a_d[head * 128 + c];
        }
#pragma unroll
        for (int i = 0; i < 4; i++) {
#pragma unroll
            for (int reg = 0; reg < 4; reg++) {
                float ps = acc[i][0][reg] * av[0] + acc[i][1][reg] * av[1]
                         + acc[i][2][reg] * av[2] + acc[i][3][reg] * av[3];
                float pd = acc[i][0][reg] * bv[0] + acc[i][1][reg] * bv[1]
                         + acc[i][2][reg] * bv[2] + acc[i][3][reg] * bv[3];
#pragma unroll
                for (int off = 8; off >= 1; off >>= 1) {
                    ps += __shfl_down(ps, off, 16);
                    pd += __shfl_down(pd, off, 16);
                }
                if (r == 0) {
                    int row128 = wy * 64 + i * 16 + quad * 4 + reg;
                    sL[wx][row128] = ps;
                    dL[wx][row128] = pd;
                }
            }
        }
        __syncthreads();
        if (tid < 128) {
            int row = bm + tid;
            if (row < M) {
                sOut[(size_t)row * H + head] = sL[0][tid] + sL[1][tid];
                dOut[(size_t)row * H + head] = dL[0][tid] + dL[1][tid];
            }
        }
    }
}

// ---------------- fused softmax+aggregation, single-pass (no max subtraction) -----------
// Exact r15 form — measured at its operating floor (73us): r16 (deeper ILP) and r17
// (grid-stride persistent blocks) both regressed; concurrency is not the binding
// constraint. Request volume (460MB/dispatch) is irreducible at bf16.

template <int HC, bool RELU>
__global__ void agg_fused_kernel(const ushort_t* __restrict__ h, const float* __restrict__ s,
                                 const float* __restrict__ dv, const int* __restrict__ rowptr,
                                 const int* __restrict__ srcS, const float* __restrict__ bias,
                                 ushort_t* __restrict__ outp, int N, int H) {
    const int TPN = HC / 8;
    const int NPB = 256 / TPN;
    int n = blockIdx.x * NPB + threadIdx.x / TPN;
    int c8 = threadIdx.x % TPN;
    if (n >= N) return;
    int head = (c8 * 8) >> 7;
    int g = c8 & 15;
    float dn = dv[(size_t)n * H + head];
    int beg = rowptr[n], end = rowptr[n + 1];
    float acc0[8] = {0.f, 0.f, 0.f, 0.f, 0.f, 0.f, 0.f, 0.f};
    float acc1[8] = {0.f, 0.f, 0.f, 0.f, 0.f, 0.f, 0.f, 0.f};
    float den = 0.f;
    for (int cb = beg; cb < end; cb += 16) {
        int je = cb + g;
        int svg = 0;
        float al = 0.f;
        if (je < end) {
            svg = srcS[je];
            float e = s[(size_t)svg * H + head] + dn;
            e = (e >= 0.f) ? e : NEG_SLOPE * e;
            al = expf(fminf(e, 80.f));
        }
        int kmax = end - cb;
        if (kmax > 16) kmax = 16;
        int k = 0;
        for (; k + 4 <= kmax; k += 4) {
            float a0 = __shfl(al, k, 16),     a1 = __shfl(al, k + 1, 16);
            float a2 = __shfl(al, k + 2, 16), a3 = __shfl(al, k + 3, 16);
            int s0 = __shfl(svg, k, 16),      s1 = __shfl(svg, k + 1, 16);
            int s2 = __shfl(svg, k + 2, 16),  s3 = __shfl(svg, k + 3, 16);
            den += a0 + a1 + a2 + a3;
            ushort8 hv0 = *(const ushort8*)(h + (size_t)s0 * HC + c8 * 8);
            ushort8 hv1 = *(const ushort8*)(h + (size_t)s1 * HC + c8 * 8);
            ushort8 hv2 = *(const ushort8*)(h + (size_t)s2 * HC + c8 * 8);
            ushort8 hv3 = *(const ushort8*)(h + (size_t)s3 * HC + c8 * 8);
#pragma unroll
            for (int kk = 0; kk < 8; kk++) {
                acc0[kk] += a0 * bf2f(hv0[kk]) + a2 * bf2f(hv2[kk]);
                acc1[kk] += a1 * bf2f(hv1[kk]) + a3 * bf2f(hv3[kk]);
            }
        }
        for (; k < kmax; k++) {
            float a0 = __shfl(al, k, 16);
            int s0 = __shfl(svg, k, 16);
            den += a0;
            ushort8 hv0 = *(const ushort8*)(h + (size_t)s0 * HC + c8 * 8);
#pragma unroll
            for (int kk = 0; kk < 8; kk++) acc0[kk] += a0 * bf2f(hv0[kk]);
        }
    }
    float inv = 1.f / den;
    float4 bv0 = ((const float4*)bias)[c8 * 2];
    float4 bv1 = ((const float4*)bias)[c8 * 2 + 1];
    float r[8];
#pragma unroll
    for (int k = 0; k < 8; k++) r[k] = (acc0[k] + acc1[k]) * inv;
    r[0] += bv0.x; r[1] += bv0.y; r[2] += bv0.z; r[3] += bv0.w;
    r[4] += bv1.x; r[5] += bv1.y; r[6] += bv1.z; r[7] += bv1.w;
    if (RELU) {
#pragma unroll
        for (int k = 0; k < 8; k++) r[k] = fmaxf(r[k], 0.f);
    }
    ushort8 o;
#pragma unroll
    for (int k = 0; k < 8; k++) o[k] = f2bf(r[k]);
    ((ushort8*)outp)[(size_t)n * TPN + c8] = o;
}

// ---------------- fully-fused classifier: relu(h3@cW1+cb1)@cW2+cb2 -> log_softmax ------
// r20: BK=64 swizzled (K=128 -> 2 k-steps). Kept single-buffered (small, ~6us).

__global__ __launch_bounds__(256, 2) void cls_fused_kernel(
    const ushort_t* __restrict__ A, const ushort_t* __restrict__ Bt,
    const float* __restrict__ cb1, const float* __restrict__ cW2,
    const float* __restrict__ cb2, float* __restrict__ out, int M) {
    __shared__ ushort_t As[128 * 64];
    __shared__ ushort_t Bs[128 * 64];
    __shared__ float l0L[128];
    __shared__ float l1L[128];
    int wg = xcd_swizzle(blockIdx.x, gridDim.x);
    int bm = wg * 128;
    int tid = threadIdx.x;
    int w = tid >> 6, lane = tid & 63;
    int wy = w >> 1, wx = w & 1;
    int r = lane & 15, quad = lane >> 4;
    int srow = lane >> 3;
    int scol = ((lane & 7) ^ srow) << 3;
    const int K = 128;
    f32x4 acc[4][4] = {};
    for (int k0 = 0; k0 < K; k0 += 64) {
#pragma unroll
        for (int it = 0; it < 4; it++) {
            int rowb = it * 32 + w * 8;
            gl_lds16(A  + (size_t)(bm + rowb + srow) * K + k0 + scol, As + rowb * 64);
            gl_lds16(Bt + (size_t)(rowb + srow) * K + k0 + scol, Bs + rowb * 64);
        }
        __syncthreads();
#pragma unroll
        for (int kh = 0; kh < 2; kh++) {
            short8 af[4], bfr[4];
            int colb = kh * 64 + quad * 16;
#pragma unroll
            for (int i = 0; i < 4; i++)
                af[i] = *(const short8*)(As + swz_us(wy * 64 + i * 16 + r, colb));
#pragma unroll
            for (int j = 0; j < 4; j++)
                bfr[j] = *(const short8*)(Bs + swz_us(wx * 64 + j * 16 + r, colb));
#pragma unroll
            for (int i = 0; i < 4; i++)
#pragma unroll
                for (int j = 0; j < 4; j++)
                    acc[i][j] = __builtin_amdgcn_mfma_f32_16x16x32_bf16(af[i], bfr[j], acc[i][j], 0, 0, 0);
        }
        __syncthreads();
    }
    if (wx == 0) {
        float c1v[4], w20[4], w21[4];
#pragma unroll
        for (int j = 0; j < 4; j++) {
            int c = j * 16 + r;
            c1v[j] = cb1[c];
            w20[j] = cW2[c * 2];
            w21[j] = cW2[c * 2 + 1];
        }
#pragma unroll
        for (int i = 0; i < 4; i++) {
#pragma unroll
            for (int reg = 0; reg < 4; reg++) {
                float ps = 0.f, pd = 0.f;
#pragma unroll
                for (int j = 0; j < 4; j++) {
                    float v = fmaxf(acc[i][j][reg] + c1v[j], 0.f);
                    ps += v * w20[j];
                    pd += v * w21[j];
                }
#pragma unroll
                for (int off = 8; off >= 1; off >>= 1) {
                    ps += __shfl_down(ps, off, 16);
                    pd += __shfl_down(pd, off, 16);
                }
                if (r == 0) {
                    int row128 = wy * 64 + i * 16 + quad * 4 + reg;
                    l0L[row128] = ps;
                    l1L[row128] = pd;
                }
            }
        }
    }
    __syncthreads();
    if (tid < 128) {
        int row = bm + tid;
        if (row < M) {
            float l0 = l0L[tid] + cb2[0];
            float l1 = l1L[tid] + cb2[1];
            float mm = fmaxf(l0, l1);
            float lse = mm + logf(expf(l0 - mm) + expf(l1 - mm));
            out[(size_t)row * 2 + 0] = l0 - lse;
            out[(size_t)row * 2 + 1] = l1 - lse;
        }
    }
}

// ---------------- launch ----------------

extern "C" void kernel_launch(void* const* d_in, const int* in_sizes, int n_in,
                              void* d_out, int out_size, void* d_ws, size_t ws_size,
                              hipStream_t stream) {
    const float* x   = (const float*)d_in[0];
    const int*   ei  = (const int*)d_in[1];
    const float* W1  = (const float*)d_in[2];
    const float* as1 = (const float*)d_in[3];
    const float* ad1 = (const float*)d_in[4];
    const float* b1  = (const float*)d_in[5];
    const float* W2  = (const float*)d_in[6];
    const float* as2 = (const float*)d_in[7];
    const float* ad2 = (const float*)d_in[8];
    const float* b2  = (const float*)d_in[9];
    const float* W3  = (const float*)d_in[10];
    const float* as3 = (const float*)d_in[11];
    const float* ad3 = (const float*)d_in[12];
    const float* b3  = (const float*)d_in[13];
    const float* cW1 = (const float*)d_in[14];
    const float* cb1 = (const float*)d_in[15];
    const float* cW2 = (const float*)d_in[16];
    const float* cb2 = (const float*)d_in[17];
    float* outp = (float*)d_out;

    const int N  = in_sizes[0] / 64;
    const int E  = in_sizes[1] / 2;
    const int E2 = E + N;
    const int NB = (N + 1023) / 1024;
    const int n4x = N * 16;

    char* ws = (char*)d_ws;
    size_t off = 0;
    auto alloc = [&](size_t bytes) -> void* {
        void* p = ws + off;
        off += (bytes + 255) & ~(size_t)255;
        return p;
    };
    ushort_t* Ab     = (ushort_t*)alloc((size_t)N * 512 * 2);
    ushort_t* Bb     = (ushort_t*)alloc((size_t)N * 512 * 2);
    ushort_t* xb     = (ushort_t*)alloc((size_t)N * 64 * 2);
    ushort_t* W1t    = (ushort_t*)alloc((size_t)512 * 64 * 2);
    ushort_t* W2t    = (ushort_t*)alloc((size_t)512 * 512 * 2);
    ushort_t* W3t    = (ushort_t*)alloc((size_t)128 * 512 * 2);
    ushort_t* cW1t   = (ushort_t*)alloc((size_t)128 * 128 * 2);
    float*    W1as   = (float*)alloc((size_t)64 * 4 * 4);
    float*    W1ad   = (float*)alloc((size_t)64 * 4 * 4);
    float*    sbuf   = (float*)alloc((size_t)N * 4 * 4);
    float*    dbuf   = (float*)alloc((size_t)N * 4 * 4);
    int*      srcS   = (int*)alloc((size_t)E2 * 4);
    int*      deg    = (int*)alloc((size_t)N * 4);
    int*      cursor = (int*)alloc((size_t)N * 4);
    int*      rowptr = (int*)alloc((size_t)(N + 1) * 4);
    int*      bsum   = (int*)alloc((size_t)256 * 4);
    (void)ws_size; (void)n_in; (void)out_size;

    // --- CSR build + conversions ---
    hipMemsetAsync(deg, 0, (size_t)N * 4, stream);
    {
        int tot = n4x + 64 * 512 + 512 * 512 + 512 * 128 + 128 * 64 + 512;
        if (E2 > tot) tot = E2;
        convert_count_kernel<<<(tot + 255) / 256, 256, 0, stream>>>(
            ei, E, N, deg, x, xb, n4x, W1, W1t, W2, W2t, W3, W3t, cW1, cW1t,
            as1, ad1, W1as, W1ad);
    }
    scan1_kernel<<<NB, 256, 0, stream>>>(deg, rowptr, bsum, N);
    scan2_kernel<<<1, 256, 0, stream>>>(bsum, rowptr, NB, N);
    scan3_kernel<<<(N + 255) / 256, 256, 0, stream>>>(bsum, rowptr, cursor, N);
    fill_csr_kernel<<<(E2 + 255) / 256, 256, 0, stream>>>(ei, E, N, cursor, srcS);

    dim3 gB(256);
    const int mt = (N + 127) / 128;           // M tiles
    const int g512 = 4 * mt;                  // 1D grids (XCD-swizzled in-kernel)
    const int g128 = mt;

    // --- layer 1 (aggregate-then-transform: 128B/edge gather instead of 1KB) ---
    score1_kernel<<<(N + 255) / 256, 256, 0, stream>>>(xb, W1as, W1ad, sbuf, dbuf, N);
    agg1x_kernel<<<(N + 7) / 8, 256, 0, stream>>>(xb, sbuf, dbuf, rowptr, srcS, Ab, N);
    tgemm1_kernel<<<g512, gB, 0, stream>>>(Ab, W1t, b1, Bb, N);

    // --- layer 2 ---
    gemm_bf16_kernel<true><<<g512, gB, 0, stream>>>(
        Bb, W2t, Ab, as2, ad2, sbuf, dbuf, 4, N, 512, 512, 4);
    agg_fused_kernel<512, true><<<(N + 3) / 4, 256, 0, stream>>>(
        Ab, sbuf, dbuf, rowptr, srcS, b2, Bb, N, 4);

    // --- layer 3 (H=1) ---
    gemm_bf16_kernel<true><<<g128, gB, 0, stream>>>(
        Bb, W3t, Ab, as3, ad3, sbuf, dbuf, 1, N, 128, 512, 1);
    agg_fused_kernel<128, false><<<(N + 15) / 16, 256, 0, stream>>>(
        Ab, sbuf, dbuf, rowptr, srcS, b3, Bb, N, 1);

    // --- fully-fused classifier ---
    cls_fused_kernel<<<g128, gB, 0, stream>>>(Bb, cW1t, cb1, cW2, cb2, outp, N);
}

// Round 9
// 365.920 us; speedup vs baseline: 1.0573x; 1.0573x over previous
//
#include <hip/hip_runtime.h>
#include <math.h>

#define NEG_SLOPE 0.2f

typedef __attribute__((ext_vector_type(8))) short short8;
typedef __attribute__((ext_vector_type(4))) float f32x4;
typedef unsigned short ushort_t;
typedef unsigned int u32;
typedef __attribute__((ext_vector_type(8))) unsigned short ushort8;
typedef __attribute__((ext_vector_type(4))) unsigned short ushort4v;

__device__ inline ushort_t f2bf(float f) {
    unsigned int u = __builtin_bit_cast(unsigned int, f);
    u += 0x7fffu + ((u >> 16) & 1u);   // RNE
    return (ushort_t)(u >> 16);
}
__device__ inline float bf2f(ushort_t u) {
    unsigned int v = ((unsigned int)u) << 16;
    return __builtin_bit_cast(float, v);
}

// async global->LDS, 16B per lane; LDS dest is wave-uniform base + lane*16 (m97 pattern)
__device__ inline void gl_lds16(const ushort_t* g, ushort_t* l) {
    __builtin_amdgcn_global_load_lds((const __attribute__((address_space(1))) u32*)g,
                                     (__attribute__((address_space(3))) u32*)l, 16, 0, 0);
}

// bijective XCD swizzle (m204): default dispatch round-robins XCDs (id%8); remap so each
// XCD owns a CONTIGUOUS chunk of tile-ids -> blocks sharing an A-panel sit on one L2.
__device__ inline int xcd_swizzle(int id, int nwg) {
    int q = nwg >> 3, r = nwg & 7;
    int xcd = id & 7, j = id >> 3;
    return (xcd < r ? xcd * (q + 1) : r * (q + 1) + (xcd - r) * q) + j;
}

// r20: BK=64 LDS tiles (row stride 128B) with XOR bank-swizzle (G4 / rule #21):
// linear gl_lds dest + inverse-permuted per-lane GLOBAL source + swizzled ds_read.
// LDS ushort index for (row, col-byte) under swizzle byte^=((row&7)<<4):
__device__ inline int swz_us(int row, int colb) {
    return row * 64 + ((colb ^ ((row & 7) << 4)) >> 1);
}

// ---------------- CSR build (discrete — r13: grid.sync ~60us each on MI355X) ------------
// r18: also computes W1as/W1ad[64x4] = per-head W1 @ a_{src,dst} (f32), enabling the
// layer-1 aggregate-then-transform trick (scores from x directly, no h1 materialization).

__global__ void convert_count_kernel(const int* __restrict__ ei, int E, int N,
                                     int* __restrict__ deg,
                                     const float* __restrict__ x, ushort_t* __restrict__ xb, int n4x,
                                     const float* __restrict__ W1, ushort_t* __restrict__ W1t,
                                     const float* __restrict__ W2, ushort_t* __restrict__ W2t,
                                     const float* __restrict__ W3, ushort_t* __restrict__ W3t,
                                     const float* __restrict__ cW1, ushort_t* __restrict__ cW1t,
                                     const float* __restrict__ as1, const float* __restrict__ ad1,
                                     float* __restrict__ W1as, float* __restrict__ W1ad) {
    int i = blockIdx.x * blockDim.x + threadIdx.x;
    if (i < E + N) {
        int d = (i < E) ? ei[E + i] : (i - E);
        atomicAdd(&deg[d], 1);
    }
    if (i < n4x) {
        float4 v = ((const float4*)x)[i];
        ushort4v o;
        o.x = f2bf(v.x); o.y = f2bf(v.y); o.z = f2bf(v.z); o.w = f2bf(v.w);
        ((ushort4v*)xb)[i] = o;
        return;
    }
    int j = i - n4x;
    if (j < 64 * 512) {
        int k = j / 512, nn = j % 512;
        W1t[(size_t)nn * 64 + k] = f2bf(W1[j]);
        return;
    }
    j -= 64 * 512;
    if (j < 512 * 512) {
        int k = j / 512, nn = j % 512;
        W2t[(size_t)nn * 512 + k] = f2bf(W2[j]);
        return;
    }
    j -= 512 * 512;
    if (j < 512 * 128) {
        int k = j / 128, nn = j % 128;
        W3t[(size_t)nn * 512 + k] = f2bf(W3[j]);
        return;
    }
    j -= 512 * 128;
    if (j < 128 * 64) {
        int k = j / 64, nn = j % 64;
        cW1t[(size_t)nn * 128 + k] = f2bf(cW1[j]);
        return;
    }
    j -= 128 * 64;
    if (j < 512) {
        // W1as[k,h] = sum_c W1[k, h*128+c] * as1[h,c]   (f32, exact fold)
        int k = j >> 3;          // 0..63
        int idx = j & 7;         // 0..7: h = idx&3, sel = idx>>2
        int h = idx & 3;
        int sel = idx >> 2;
        const float* av = sel ? ad1 : as1;
        float* outw = sel ? W1ad : W1as;
        const float* wrow = W1 + (size_t)k * 512 + h * 128;
        const float* arow = av + h * 128;
        float acc = 0.f;
        for (int c = 0; c < 128; c++) acc += wrow[c] * arow[c];
        outw[k * 4 + h] = acc;
    }
}

__global__ void scan1_kernel(const int* __restrict__ deg, int* __restrict__ rowptr,
                             int* __restrict__ bsum, int N) {
    __shared__ int sdata[256];
    int t = threadIdx.x;
    int base = blockIdx.x * 1024 + t * 4;
    int v[4];
#pragma unroll
    for (int k = 0; k < 4; k++) v[k] = (base + k < N) ? deg[base + k] : 0;
    int s = v[0] + v[1] + v[2] + v[3];
    sdata[t] = s;
    __syncthreads();
    for (int off = 1; off < 256; off <<= 1) {
        int x = (t >= off) ? sdata[t - off] : 0;
        __syncthreads();
        sdata[t] += x;
        __syncthreads();
    }
    int p = sdata[t] - s;
    if (t == 255) bsum[blockIdx.x] = sdata[255];
#pragma unroll
    for (int k = 0; k < 4; k++) {
        if (base + k < N) rowptr[base + k] = p;
        p += v[k];
    }
}

__global__ void scan2_kernel(int* __restrict__ bsum, int* __restrict__ rowptr, int nb, int N) {
    __shared__ int sh[256];
    int t = threadIdx.x;
    int v = (t < nb) ? bsum[t] : 0;
    sh[t] = v;
    __syncthreads();
    for (int off = 1; off < 256; off <<= 1) {
        int x = (t >= off) ? sh[t - off] : 0;
        __syncthreads();
        sh[t] += x;
        __syncthreads();
    }
    if (t < nb) bsum[t] = sh[t] - v;
    if (t == 255) rowptr[N] = sh[255];
}

__global__ void scan3_kernel(const int* __restrict__ bsum, int* __restrict__ rowptr,
                             int* __restrict__ cursor, int N) {
    int i = blockIdx.x * blockDim.x + threadIdx.x;
    if (i < N) {
        int v = rowptr[i] + bsum[i >> 10];
        rowptr[i] = v;
        cursor[i] = v;
    }
}

__global__ void fill_csr_kernel(const int* __restrict__ ei, int E, int N,
                                int* __restrict__ cursor, int* __restrict__ srcS) {
    int e = blockIdx.x * blockDim.x + threadIdx.x;
    if (e >= E + N) return;
    int s, d;
    if (e < E) { s = ei[e]; d = ei[E + e]; }
    else       { s = e - E; d = e - E; }
    int pos = atomicAdd(&cursor[d], 1);
    srcS[pos] = s;
}

// ---------------- layer-1 scores directly from x: s = x @ W1as, d = x @ W1ad ------------

__global__ __launch_bounds__(256) void score1_kernel(const ushort_t* __restrict__ xb,
                                                     const float* __restrict__ W1as,
                                                     const float* __restrict__ W1ad,
                                                     float* __restrict__ sOut,
                                                     float* __restrict__ dOut, int N) {
    __shared__ float wa[256];
    __shared__ float wd[256];
    int t = threadIdx.x;
    wa[t] = W1as[t];
    wd[t] = W1ad[t];
    __syncthreads();
    int n = blockIdx.x * 256 + t;
    if (n >= N) return;
    const ushort_t* xr = xb + (size_t)n * 64;
    float s_[4] = {0.f, 0.f, 0.f, 0.f};
    float d_[4] = {0.f, 0.f, 0.f, 0.f};
#pragma unroll
    for (int k8 = 0; k8 < 8; k8++) {
        ushort8 xv = *(const ushort8*)(xr + k8 * 8);
#pragma unroll
        for (int kk = 0; kk < 8; kk++) {
            float xf = bf2f(xv[kk]);
            int k = k8 * 8 + kk;
#pragma unroll
            for (int h = 0; h < 4; h++) {
                s_[h] += xf * wa[k * 4 + h];
                d_[h] += xf * wd[k * 4 + h];
            }
        }
    }
#pragma unroll
    for (int h = 0; h < 4; h++) {
        sOut[(size_t)n * 4 + h] = s_[h];
        dOut[(size_t)n * 4 + h] = d_[h];
    }
}

// ---------------- layer-1 aggregate-then-transform: aggX[n,h,64] = norm(sum alpha x[src])
// 32 threads/node: h = c>>3 owns dims (c&7)*8..+8 of head h; alpha-phase thread c covers
// (edge c&7, head c>>3). Gather is 128B/edge (x row) vs 1KB (h1 row) — 8x less traffic,
// and the 6.4MB x array is L2-resident.

__global__ void agg1x_kernel(const ushort_t* __restrict__ xb, const float* __restrict__ s,
                             const float* __restrict__ dv, const int* __restrict__ rowptr,
                             const int* __restrict__ srcS, ushort_t* __restrict__ outp, int N) {
    int c = threadIdx.x & 31;
    int slot = threadIdx.x >> 5;
    int n = blockIdx.x * 8 + slot;
    if (n >= N) return;
    int h = c >> 3;
    int d8 = c & 7;
    float dn = dv[(size_t)n * 4 + h];
    int beg = rowptr[n], end = rowptr[n + 1];
    float acc[8] = {0.f, 0.f, 0.f, 0.f, 0.f, 0.f, 0.f, 0.f};
    float den = 0.f;
    for (int cb = beg; cb < end; cb += 8) {
        int j = cb + d8;   // d8 doubles as my alpha-edge index
        int svg = 0;
        float al = 0.f;
        if (j < end) {
            svg = srcS[j];
            float e = s[(size_t)svg * 4 + h] + dn;
            e = (e >= 0.f) ? e : NEG_SLOPE * e;
            al = expf(fminf(e, 80.f));
        }
        int kmax = end - cb;
        if (kmax > 8) kmax = 8;
        for (int q = 0; q < kmax; q++) {
            float a = __shfl(al, h * 8 + q, 32);   // alpha(edge q, my head)
            int sq = __shfl(svg, q, 32);           // src(edge q) from lane q (head 0)
            den += a;
            ushort8 xv = *(const ushort8*)(xb + (size_t)sq * 64 + d8 * 8);
#pragma unroll
            for (int kk = 0; kk < 8; kk++) acc[kk] += a * bf2f(xv[kk]);
        }
    }
    float inv = 1.f / den;
    ushort8 o;
#pragma unroll
    for (int kk = 0; kk < 8; kk++) o[kk] = f2bf(acc[kk] * inv);
    ((ushort8*)outp)[(size_t)n * 32 + c] = o;   // out row [N,256]: h*64 + d8*8
}

// ---------------- layer-1 transform: Bb[n,512] = relu(blockdiag(aggX) @ W1 + b1) --------
// Output col-block = head; A cols = [head*64, head*64+64), lda=256. K=64 -> single BK=64
// step (r20), 2 barriers total. XOR-swizzled LDS (see r20 note at top).

__global__ __launch_bounds__(256, 2) void tgemm1_kernel(
    const ushort_t* __restrict__ A, const ushort_t* __restrict__ Bt,
    const float* __restrict__ bias, ushort_t* __restrict__ C, int M) {
    __shared__ ushort_t As[128 * 64];
    __shared__ ushort_t Bs[128 * 64];
    int wg = xcd_swizzle(blockIdx.x, gridDim.x);
    int bm = (wg >> 2) * 128;
    int head = wg & 3;
    int bn = head * 128;
    int tid = threadIdx.x;
    int w = tid >> 6, lane = tid & 63;
    int wy = w >> 1, wx = w & 1;
    int r = lane & 15, quad = lane >> 4;
    int srow = lane >> 3;                       // 0..7
    int scol = ((lane & 7) ^ srow) << 3;        // inverse-permuted source col (ushorts)
    f32x4 acc[4][4] = {};
#pragma unroll
    for (int it = 0; it < 4; it++) {
        int rowb = it * 32 + w * 8;
        gl_lds16(A  + (size_t)(bm + rowb + srow) * 256 + head * 64 + scol, As + rowb * 64);
        gl_lds16(Bt + (size_t)(bn + rowb + srow) * 64 + scol, Bs + rowb * 64);
    }
    __syncthreads();
#pragma unroll
    for (int kh = 0; kh < 2; kh++) {
        short8 af[4], bfr[4];
        int colb = kh * 64 + quad * 16;
#pragma unroll
        for (int i = 0; i < 4; i++)
            af[i] = *(const short8*)(As + swz_us(wy * 64 + i * 16 + r, colb));
#pragma unroll
        for (int j = 0; j < 4; j++)
            bfr[j] = *(const short8*)(Bs + swz_us(wx * 64 + j * 16 + r, colb));
#pragma unroll
        for (int i = 0; i < 4; i++)
#pragma unroll
            for (int j = 0; j < 4; j++)
                acc[i][j] = __builtin_amdgcn_mfma_f32_16x16x32_bf16(af[i], bfr[j], acc[i][j], 0, 0, 0);
    }
#pragma unroll
    for (int i = 0; i < 4; i++) {
        int rowb = bm + wy * 64 + i * 16 + quad * 4;
#pragma unroll
        for (int j = 0; j < 4; j++) {
            int col = bn + wx * 64 + j * 16 + r;
            float bv = bias[col];
#pragma unroll
            for (int reg = 0; reg < 4; reg++) {
                int row = rowb + reg;
                if (row < M) C[(size_t)row * 512 + col] = f2bf(fmaxf(acc[i][j][reg] + bv, 0.f));
            }
        }
    }
}

// ---------------- bf16 MFMA GEMM w/ global_load_lds staging + optional fused scores -----
// r19: 1D grid + bijective XCD swizzle (T1).
// r20: BK=64 + XOR-swizzled LDS (quarter-wave 8-way conflict -> 2-way free). 366.4us.
// r21 FAILED (REVERTED): 2-phase LDS double-buffer. LDS 33->65KB/block halved resident
//   blocks/CU (4->2, LDS-limited; launch_bounds(256,2) only guarantees 2) -> TLP loss
//   exceeded the 1-deep prefetch gain: 366.4->386.9us (+20). m132/m99 lesson replayed:
//   do NOT trade occupancy for pipeline depth here. Single-buffer is the keeper.

template <bool SCORES>
__global__ __launch_bounds__(256, 2) void gemm_bf16_kernel(
    const ushort_t* __restrict__ A, const ushort_t* __restrict__ Bt,
    ushort_t* __restrict__ C,
    const float* __restrict__ a_s, const float* __restrict__ a_d,
    float* __restrict__ sOut, float* __restrict__ dOut, int H,
    int M, int Ncols, int K, int nbx) {
    __shared__ ushort_t As[128 * 64];
    __shared__ ushort_t Bs[128 * 64];
    __shared__ float sL[2][128];
    __shared__ float dL[2][128];
    int wg = xcd_swizzle(blockIdx.x, gridDim.x);
    int bm = (wg / nbx) * 128, bn = (wg % nbx) * 128;
    int tid = threadIdx.x;
    int w = tid >> 6, lane = tid & 63;
    int wy = w >> 1, wx = w & 1;
    int r = lane & 15, quad = lane >> 4;
    int srow = lane >> 3;                       // 0..7
    int scol = ((lane & 7) ^ srow) << 3;        // inverse-permuted source col (ushorts)
    f32x4 acc[4][4] = {};
    for (int k0 = 0; k0 < K; k0 += 64) {
#pragma unroll
        for (int it = 0; it < 4; it++) {
            int rowb = it * 32 + w * 8;
            gl_lds16(A  + (size_t)(bm + rowb + srow) * K + k0 + scol, As + rowb * 64);
            gl_lds16(Bt + (size_t)(bn + rowb + srow) * K + k0 + scol, Bs + rowb * 64);
        }
        __syncthreads();
#pragma unroll
        for (int kh = 0; kh < 2; kh++) {
            short8 af[4], bfr[4];
            int colb = kh * 64 + quad * 16;
#pragma unroll
            for (int i = 0; i < 4; i++)
                af[i] = *(const short8*)(As + swz_us(wy * 64 + i * 16 + r, colb));
#pragma unroll
            for (int j = 0; j < 4; j++)
                bfr[j] = *(const short8*)(Bs + swz_us(wx * 64 + j * 16 + r, colb));
#pragma unroll
            for (int i = 0; i < 4; i++)
#pragma unroll
                for (int j = 0; j < 4; j++)
                    acc[i][j] = __builtin_amdgcn_mfma_f32_16x16x32_bf16(af[i], bfr[j], acc[i][j], 0, 0, 0);
        }
        __syncthreads();
    }
#pragma unroll
    for (int i = 0; i < 4; i++) {
        int rowb = bm + wy * 64 + i * 16 + quad * 4;
#pragma unroll
        for (int j = 0; j < 4; j++) {
            int col = bn + wx * 64 + j * 16 + r;
            if (col >= Ncols) continue;
#pragma unroll
            for (int reg = 0; reg < 4; reg++) {
                int row = rowb + reg;
                if (row < M) C[(size_t)row * Ncols + col] = f2bf(acc[i][j][reg]);
            }
        }
    }
    if (SCORES) {
        int head = bn >> 7;
        float av[4], bv[4];
#pragma unroll
        for (int j = 0; j < 4; j++) {
            int c = wx * 64 + j * 16 + r;
            av[j] = a_s[head * 128 + c];
            bv[j] = a_d[head * 128 + c];
        }
#pragma unroll
        for (int i = 0; i < 4; i++) {
#pragma unroll
            for (int reg = 0; reg < 4; reg++) {
                float ps = acc[i][0][reg] * av[0] + acc[i][1][reg] * av[1]
                         + acc[i][2][reg] * av[2] + acc[i][3][reg] * av[3];
                float pd = acc[i][0][reg] * bv[0] + acc[i][1][reg] * bv[1]
                         + acc[i][2][reg] * bv[2] + acc[i][3][reg] * bv[3];
#pragma unroll
                for (int off = 8; off >= 1; off >>= 1) {
                    ps += __shfl_down(ps, off, 16);
                    pd += __shfl_down(pd, off, 16);
                }
                if (r == 0) {
                    int row128 = wy * 64 + i * 16 + quad * 4 + reg;
                    sL[wx][row128] = ps;
                    dL[wx][row128] = pd;
                }
            }
        }
        __syncthreads();
        if (tid < 128) {
            int row = bm + tid;
            if (row < M) {
                sOut[(size_t)row * H + head] = sL[0][tid] + sL[1][tid];
                dOut[(size_t)row * H + head] = dL[0][tid] + dL[1][tid];
            }
        }
    }
}

// ---------------- fused softmax+aggregation, single-pass (no max subtraction) -----------
// Exact r15 form — measured at its operating floor (73us): r16 (deeper ILP) and r17
// (grid-stride persistent blocks) both regressed; concurrency is not the binding
// constraint. Request volume (460MB/dispatch) is irreducible at bf16.

template <int HC, bool RELU>
__global__ void agg_fused_kernel(const ushort_t* __restrict__ h, const float* __restrict__ s,
                                 const float* __restrict__ dv, const int* __restrict__ rowptr,
                                 const int* __restrict__ srcS, const float* __restrict__ bias,
                                 ushort_t* __restrict__ outp, int N, int H) {
    const int TPN = HC / 8;
    const int NPB = 256 / TPN;
    int n = blockIdx.x * NPB + threadIdx.x / TPN;
    int c8 = threadIdx.x % TPN;
    if (n >= N) return;
    int head = (c8 * 8) >> 7;
    int g = c8 & 15;
    float dn = dv[(size_t)n * H + head];
    int beg = rowptr[n], end = rowptr[n + 1];
    float acc0[8] = {0.f, 0.f, 0.f, 0.f, 0.f, 0.f, 0.f, 0.f};
    float acc1[8] = {0.f, 0.f, 0.f, 0.f, 0.f, 0.f, 0.f, 0.f};
    float den = 0.f;
    for (int cb = beg; cb < end; cb += 16) {
        int je = cb + g;
        int svg = 0;
        float al = 0.f;
        if (je < end) {
            svg = srcS[je];
            float e = s[(size_t)svg * H + head] + dn;
            e = (e >= 0.f) ? e : NEG_SLOPE * e;
            al = expf(fminf(e, 80.f));
        }
        int kmax = end - cb;
        if (kmax > 16) kmax = 16;
        int k = 0;
        for (; k + 4 <= kmax; k += 4) {
            float a0 = __shfl(al, k, 16),     a1 = __shfl(al, k + 1, 16);
            float a2 = __shfl(al, k + 2, 16), a3 = __shfl(al, k + 3, 16);
            int s0 = __shfl(svg, k, 16),      s1 = __shfl(svg, k + 1, 16);
            int s2 = __shfl(svg, k + 2, 16),  s3 = __shfl(svg, k + 3, 16);
            den += a0 + a1 + a2 + a3;
            ushort8 hv0 = *(const ushort8*)(h + (size_t)s0 * HC + c8 * 8);
            ushort8 hv1 = *(const ushort8*)(h + (size_t)s1 * HC + c8 * 8);
            ushort8 hv2 = *(const ushort8*)(h + (size_t)s2 * HC + c8 * 8);
            ushort8 hv3 = *(const ushort8*)(h + (size_t)s3 * HC + c8 * 8);
#pragma unroll
            for (int kk = 0; kk < 8; kk++) {
                acc0[kk] += a0 * bf2f(hv0[kk]) + a2 * bf2f(hv2[kk]);
                acc1[kk] += a1 * bf2f(hv1[kk]) + a3 * bf2f(hv3[kk]);
            }
        }
        for (; k < kmax; k++) {
            float a0 = __shfl(al, k, 16);
            int s0 = __shfl(svg, k, 16);
            den += a0;
            ushort8 hv0 = *(const ushort8*)(h + (size_t)s0 * HC + c8 * 8);
#pragma unroll
            for (int kk = 0; kk < 8; kk++) acc0[kk] += a0 * bf2f(hv0[kk]);
        }
    }
    float inv = 1.f / den;
    float4 bv0 = ((const float4*)bias)[c8 * 2];
    float4 bv1 = ((const float4*)bias)[c8 * 2 + 1];
    float r[8];
#pragma unroll
    for (int k = 0; k < 8; k++) r[k] = (acc0[k] + acc1[k]) * inv;
    r[0] += bv0.x; r[1] += bv0.y; r[2] += bv0.z; r[3] += bv0.w;
    r[4] += bv1.x; r[5] += bv1.y; r[6] += bv1.z; r[7] += bv1.w;
    if (RELU) {
#pragma unroll
        for (int k = 0; k < 8; k++) r[k] = fmaxf(r[k], 0.f);
    }
    ushort8 o;
#pragma unroll
    for (int k = 0; k < 8; k++) o[k] = f2bf(r[k]);
    ((ushort8*)outp)[(size_t)n * TPN + c8] = o;
}

// ---------------- fully-fused classifier: relu(h3@cW1+cb1)@cW2+cb2 -> log_softmax ------
// r20: BK=64 swizzled (K=128 -> 2 k-steps).

__global__ __launch_bounds__(256, 2) void cls_fused_kernel(
    const ushort_t* __restrict__ A, const ushort_t* __restrict__ Bt,
    const float* __restrict__ cb1, const float* __restrict__ cW2,
    const float* __restrict__ cb2, float* __restrict__ out, int M) {
    __shared__ ushort_t As[128 * 64];
    __shared__ ushort_t Bs[128 * 64];
    __shared__ float l0L[128];
    __shared__ float l1L[128];
    int wg = xcd_swizzle(blockIdx.x, gridDim.x);
    int bm = wg * 128;
    int tid = threadIdx.x;
    int w = tid >> 6, lane = tid & 63;
    int wy = w >> 1, wx = w & 1;
    int r = lane & 15, quad = lane >> 4;
    int srow = lane >> 3;
    int scol = ((lane & 7) ^ srow) << 3;
    const int K = 128;
    f32x4 acc[4][4] = {};
    for (int k0 = 0; k0 < K; k0 += 64) {
#pragma unroll
        for (int it = 0; it < 4; it++) {
            int rowb = it * 32 + w * 8;
            gl_lds16(A  + (size_t)(bm + rowb + srow) * K + k0 + scol, As + rowb * 64);
            gl_lds16(Bt + (size_t)(rowb + srow) * K + k0 + scol, Bs + rowb * 64);
        }
        __syncthreads();
#pragma unroll
        for (int kh = 0; kh < 2; kh++) {
            short8 af[4], bfr[4];
            int colb = kh * 64 + quad * 16;
#pragma unroll
            for (int i = 0; i < 4; i++)
                af[i] = *(const short8*)(As + swz_us(wy * 64 + i * 16 + r, colb));
#pragma unroll
            for (int j = 0; j < 4; j++)
                bfr[j] = *(const short8*)(Bs + swz_us(wx * 64 + j * 16 + r, colb));
#pragma unroll
            for (int i = 0; i < 4; i++)
#pragma unroll
                for (int j = 0; j < 4; j++)
                    acc[i][j] = __builtin_amdgcn_mfma_f32_16x16x32_bf16(af[i], bfr[j], acc[i][j], 0, 0, 0);
        }
        __syncthreads();
    }
    if (wx == 0) {
        float c1v[4], w20[4], w21[4];
#pragma unroll
        for (int j = 0; j < 4; j++) {
            int c = j * 16 + r;
            c1v[j] = cb1[c];
            w20[j] = cW2[c * 2];
            w21[j] = cW2[c * 2 + 1];
        }
#pragma unroll
        for (int i = 0; i < 4; i++) {
#pragma unroll
            for (int reg = 0; reg < 4; reg++) {
                float ps = 0.f, pd = 0.f;
#pragma unroll
                for (int j = 0; j < 4; j++) {
                    float v = fmaxf(acc[i][j][reg] + c1v[j], 0.f);
                    ps += v * w20[j];
                    pd += v * w21[j];
                }
#pragma unroll
                for (int off = 8; off >= 1; off >>= 1) {
                    ps += __shfl_down(ps, off, 16);
                    pd += __shfl_down(pd, off, 16);
                }
                if (r == 0) {
                    int row128 = wy * 64 + i * 16 + quad * 4 + reg;
                    l0L[row128] = ps;
                    l1L[row128] = pd;
                }
            }
        }
    }
    __syncthreads();
    if (tid < 128) {
        int row = bm + tid;
        if (row < M) {
            float l0 = l0L[tid] + cb2[0];
            float l1 = l1L[tid] + cb2[1];
            float mm = fmaxf(l0, l1);
            float lse = mm + logf(expf(l0 - mm) + expf(l1 - mm));
            out[(size_t)row * 2 + 0] = l0 - lse;
            out[(size_t)row * 2 + 1] = l1 - lse;
        }
    }
}

// ---------------- launch ----------------

extern "C" void kernel_launch(void* const* d_in, const int* in_sizes, int n_in,
                              void* d_out, int out_size, void* d_ws, size_t ws_size,
                              hipStream_t stream) {
    const float* x   = (const float*)d_in[0];
    const int*   ei  = (const int*)d_in[1];
    const float* W1  = (const float*)d_in[2];
    const float* as1 = (const float*)d_in[3];
    const float* ad1 = (const float*)d_in[4];
    const float* b1  = (const float*)d_in[5];
    const float* W2  = (const float*)d_in[6];
    const float* as2 = (const float*)d_in[7];
    const float* ad2 = (const float*)d_in[8];
    const float* b2  = (const float*)d_in[9];
    const float* W3  = (const float*)d_in[10];
    const float* as3 = (const float*)d_in[11];
    const float* ad3 = (const float*)d_in[12];
    const float* b3  = (const float*)d_in[13];
    const float* cW1 = (const float*)d_in[14];
    const float* cb1 = (const float*)d_in[15];
    const float* cW2 = (const float*)d_in[16];
    const float* cb2 = (const float*)d_in[17];
    float* outp = (float*)d_out;

    const int N  = in_sizes[0] / 64;
    const int E  = in_sizes[1] / 2;
    const int E2 = E + N;
    const int NB = (N + 1023) / 1024;
    const int n4x = N * 16;

    char* ws = (char*)d_ws;
    size_t off = 0;
    auto alloc = [&](size_t bytes) -> void* {
        void* p = ws + off;
        off += (bytes + 255) & ~(size_t)255;
        return p;
    };
    ushort_t* Ab     = (ushort_t*)alloc((size_t)N * 512 * 2);
    ushort_t* Bb     = (ushort_t*)alloc((size_t)N * 512 * 2);
    ushort_t* xb     = (ushort_t*)alloc((size_t)N * 64 * 2);
    ushort_t* W1t    = (ushort_t*)alloc((size_t)512 * 64 * 2);
    ushort_t* W2t    = (ushort_t*)alloc((size_t)512 * 512 * 2);
    ushort_t* W3t    = (ushort_t*)alloc((size_t)128 * 512 * 2);
    ushort_t* cW1t   = (ushort_t*)alloc((size_t)128 * 128 * 2);
    float*    W1as   = (float*)alloc((size_t)64 * 4 * 4);
    float*    W1ad   = (float*)alloc((size_t)64 * 4 * 4);
    float*    sbuf   = (float*)alloc((size_t)N * 4 * 4);
    float*    dbuf   = (float*)alloc((size_t)N * 4 * 4);
    int*      srcS   = (int*)alloc((size_t)E2 * 4);
    int*      deg    = (int*)alloc((size_t)N * 4);
    int*      cursor = (int*)alloc((size_t)N * 4);
    int*      rowptr = (int*)alloc((size_t)(N + 1) * 4);
    int*      bsum   = (int*)alloc((size_t)256 * 4);
    (void)ws_size; (void)n_in; (void)out_size;

    // --- CSR build + conversions ---
    hipMemsetAsync(deg, 0, (size_t)N * 4, stream);
    {
        int tot = n4x + 64 * 512 + 512 * 512 + 512 * 128 + 128 * 64 + 512;
        if (E2 > tot) tot = E2;
        convert_count_kernel<<<(tot + 255) / 256, 256, 0, stream>>>(
            ei, E, N, deg, x, xb, n4x, W1, W1t, W2, W2t, W3, W3t, cW1, cW1t,
            as1, ad1, W1as, W1ad);
    }
    scan1_kernel<<<NB, 256, 0, stream>>>(deg, rowptr, bsum, N);
    scan2_kernel<<<1, 256, 0, stream>>>(bsum, rowptr, NB, N);
    scan3_kernel<<<(N + 255) / 256, 256, 0, stream>>>(bsum, rowptr, cursor, N);
    fill_csr_kernel<<<(E2 + 255) / 256, 256, 0, stream>>>(ei, E, N, cursor, srcS);

    dim3 gB(256);
    const int mt = (N + 127) / 128;           // M tiles
    const int g512 = 4 * mt;                  // 1D grids (XCD-swizzled in-kernel)
    const int g128 = mt;

    // --- layer 1 (aggregate-then-transform: 128B/edge gather instead of 1KB) ---
    score1_kernel<<<(N + 255) / 256, 256, 0, stream>>>(xb, W1as, W1ad, sbuf, dbuf, N);
    agg1x_kernel<<<(N + 7) / 8, 256, 0, stream>>>(xb, sbuf, dbuf, rowptr, srcS, Ab, N);
    tgemm1_kernel<<<g512, gB, 0, stream>>>(Ab, W1t, b1, Bb, N);

    // --- layer 2 ---
    gemm_bf16_kernel<true><<<g512, gB, 0, stream>>>(
        Bb, W2t, Ab, as2, ad2, sbuf, dbuf, 4, N, 512, 512, 4);
    agg_fused_kernel<512, true><<<(N + 3) / 4, 256, 0, stream>>>(
        Ab, sbuf, dbuf, rowptr, srcS, b2, Bb, N, 4);

    // --- layer 3 (H=1) ---
    gemm_bf16_kernel<true><<<g128, gB, 0, stream>>>(
        Bb, W3t, Ab, as3, ad3, sbuf, dbuf, 1, N, 128, 512, 1);
    agg_fused_kernel<128, false><<<(N + 15) / 16, 256, 0, stream>>>(
        Ab, sbuf, dbuf, rowptr, srcS, b3, Bb, N, 1);

    // --- fully-fused classifier ---
    cls_fused_kernel<<<g128, gB, 0, stream>>>(Bb, cW1t, cb1, cW2, cb2, outp, N);
}